// Round 8
// baseline (2208.291 us; speedup 1.0000x reference)
//
#include <hip/hip_runtime.h>
#include <math.h>
#include <stdint.h>

typedef __bf16 bf16_t;
typedef __bf16 bf16x8 __attribute__((ext_vector_type(8)));
typedef __bf16 bf16x4 __attribute__((ext_vector_type(4)));
typedef float f32x4 __attribute__((ext_vector_type(4)));

#define NLAYER 6
#define DMODEL 768
#define NHEAD 12
#define DHEAD 64
#define SEQ 512
#define BATCH 8
#define MROWS 4096 /* BATCH*SEQ */
#define DFFN 3072

// ---------- helpers ----------

__device__ inline void async_load16(const void* g, void* lds) {
  const __attribute__((address_space(1))) void* gp =
      (const __attribute__((address_space(1))) void*)(uintptr_t)g;
  __attribute__((address_space(3))) void* lp =
      (__attribute__((address_space(3))) void*)(uint32_t)(uintptr_t)lds;
  __builtin_amdgcn_global_load_lds(gp, lp, 16, 0, 0);
}

#define VMCNT(n) __builtin_amdgcn_s_waitcnt(0x0F70 | (n))
#define LGKM0 __builtin_amdgcn_s_waitcnt(0xC07F) /* lgkmcnt(0) only */

__device__ inline float wsum(float v) {
#pragma unroll
  for (int o = 32; o > 0; o >>= 1) v += __shfl_xor(v, o, 64);
  return v;
}

__device__ inline float gelu_f(float x) {
  // 0.5x(1+tanh(u)) == x / (1 + exp(-2u)); hardware v_exp_f32 path
  const float u = x + 0.044715f * x * x * x;
  return x / (1.0f + __expf(-1.5957691216057308f * u));
}

struct GP {
  const bf16_t* A;
  const bf16_t* B;
  const float* bias;   // [N] or null (ignored when ksplit>1)
  float* outF;         // f32 out (partial base 0..zext-1 when ksplit>1)
  float* pF2;          // partial base for z >= zext (or null)
  bf16_t* outB;        // bf16 out or null
  int M, N, K;
  int lda, ldb, ldc;
  long pstride;  // partial-buffer stride (elements) for ksplit>1
  int act;       // 1 = gelu
  int ksplit;
  int zext;      // first z index routed to pF2
};

// ---------- 128x128 GEMM ----------
// r6 kernel (triple-buffer, vmcnt(8), conflict-free swizzle, LDS-bounce
// epilogue) + XCD-aware block swizzle (T1): same-B-panel blocks co-locate
// on one XCD's L2. All grids have (gx*gy)%8==0 (bijectivity requirement).
__global__ __launch_bounds__(256) void gemm128(GP p) {
  __shared__ __align__(16) char smem[49152];
  bf16_t* As = (bf16_t*)smem;            // [3][128*32]
  bf16_t* Bs = (bf16_t*)(smem + 24576);  // [3][128*32]
  const int tid = threadIdx.x;
  const int wave = tid >> 6, lane = tid & 63;
  const int wr = wave >> 1, wc = wave & 1;
  const int lrow = lane & 15, kq = lane >> 4;
  const int swz = (kq ^ ((lrow >> 1) & 3)) * 8;  // read slot (elements)
  const int sr = tid >> 2;
  const int scs = ((tid & 3) ^ ((tid >> 3) & 3)) << 3;  // inv-swizzled src col

  // XCD-aware remap of (x,y): blocks with lin%8==k (same XCD) get a
  // contiguous nlin band -> contiguous n-tiles -> B panel L2-resident.
  const int gx = gridDim.x;
  const int nxy = gx * (int)gridDim.y;
  const int lin = (int)blockIdx.x + gx * (int)blockIdx.y;
  const int nlin = (lin & 7) * (nxy >> 3) + (lin >> 3);
  const int m0 = (nlin % gx) * 128;
  const int n0 = (nlin / gx) * 128;
  const int zs = (int)blockIdx.z;

  const int kc = p.K / p.ksplit;
  const int kstart = zs * kc;
  const int kend = kstart + kc;

  auto stage = [&](int k0, int buf) {
#pragma unroll
    for (int r = 0; r < 2; ++r)
      async_load16(p.A + (long)(m0 + r * 64 + sr) * p.lda + (k0 + scs),
                   As + buf * 4096 + (r * 64 + wave * 16) * 32);
#pragma unroll
    for (int r = 0; r < 2; ++r)
      async_load16(p.B + (long)(n0 + r * 64 + sr) * p.ldb + (k0 + scs),
                   Bs + buf * 4096 + (r * 64 + wave * 16) * 32);
  };

  f32x4 acc[4][4] = {};
  stage(kstart, 0);
  if (kstart + 32 < kend) stage(kstart + 32, 1);
  int cur = 0, nxt = 1, fut = 2;

  for (int k0 = kstart; k0 < kend; k0 += 32) {
    if (k0 + 64 < kend) {
      stage(k0 + 64, fut);  // fut's last readers finished 2 barriers ago
      VMCNT(8);             // cur's 4 loads (issued 2 iters ago) landed
    } else if (k0 + 32 < kend) {
      VMCNT(4);
    } else {
      VMCNT(0);
    }
    __builtin_amdgcn_s_barrier();

    const int cb = cur * 4096;
    bf16x8 af[4], bfr[4];
#pragma unroll
    for (int i = 0; i < 4; ++i)
      af[i] = *(const bf16x8*)&As[cb + (wr * 64 + i * 16 + lrow) * 32 + swz];
#pragma unroll
    for (int j = 0; j < 4; ++j)
      bfr[j] = *(const bf16x8*)&Bs[cb + (wc * 64 + j * 16 + lrow) * 32 + swz];
#pragma unroll
    for (int i = 0; i < 4; ++i)
#pragma unroll
      for (int j = 0; j < 4; ++j)
        acc[i][j] = __builtin_amdgcn_mfma_f32_16x16x32_bf16(af[i], bfr[j], acc[i][j], 0, 0, 0);

    __builtin_amdgcn_s_barrier();  // all waves done reading cur before reuse
    const int t = cur; cur = nxt; nxt = fut; fut = t;
  }

  // ---- epilogue: LDS-bounce coalesced stores (staging LDS is dead) ----
  const int colbase = n0 + wc * 64;
  const int lc = lrow;  // lane & 15
  float* eb = (float*)(smem + wave * 4608);  // per-wave 4.6KB private

  if (p.ksplit > 1) {
    float* po = (zs < p.zext) ? p.outF + (long)zs * p.pstride
                              : p.pF2 + (long)(zs - p.zext) * p.pstride;
#pragma unroll
    for (int i = 0; i < 4; ++i) {
      const int rg0 = m0 + wr * 64 + i * 16;
#pragma unroll
      for (int j = 0; j < 4; ++j)
#pragma unroll
        for (int r = 0; r < 4; ++r)
          eb[(kq * 4 + r) * 68 + j * 16 + lc] = acc[i][j][r];
      LGKM0;
#pragma unroll
      for (int q = 0; q < 4; ++q) {
        const int row = q * 4 + kq;
        const f32x4 v = *(const f32x4*)&eb[row * 68 + lc * 4];
        *(f32x4*)&po[(long)(rg0 + row) * p.ldc + colbase + lc * 4] = v;
      }
      LGKM0;  // reads retired before next i overwrites
    }
  } else {
    float bs[4] = {0.f, 0.f, 0.f, 0.f};
    if (p.bias) {
#pragma unroll
      for (int j = 0; j < 4; ++j) bs[j] = p.bias[colbase + j * 16 + lc];
    }
    bf16_t* bh = (bf16_t*)eb;  // stride 72 (144B = 9x16B, quad-rotating)
    const int l8r = lane >> 3, l8c = lane & 7;
#pragma unroll
    for (int i = 0; i < 4; ++i) {
      const int rg0 = m0 + wr * 64 + i * 16;
#pragma unroll
      for (int j = 0; j < 4; ++j)
#pragma unroll
        for (int r = 0; r < 4; ++r) {
          float y = acc[i][j][r] + bs[j];
          if (p.act) y = gelu_f(y);
          bh[(kq * 4 + r) * 72 + j * 16 + lc] = (bf16_t)y;
        }
      LGKM0;
      if (p.outB) {
#pragma unroll
        for (int q = 0; q < 2; ++q) {
          const int row = q * 8 + l8r;
          const bf16x8 v = *(const bf16x8*)&bh[row * 72 + l8c * 8];
          *(bf16x8*)&p.outB[(long)(rg0 + row) * p.ldc + colbase + l8c * 8] = v;
        }
      }
      LGKM0;
    }
  }
}

// ---------- fused flash attention ----------
#define QT 64
#define KT 128
#define VPAD 136

// V-transpose store swizzle: VALUE of row d (= c8+j) is stored at position
// c8 + (j ^ sx) where sx = d>>3 (r7 BUG: stored vv[j^sx] there, i.e. the
// linear layout, while reads expected the swizzle -> permuted V. Fixed to
// vv[j]). Write banks: (j^sx)*4 + (row>>1) over the wave = 32 banks x 2-way
// (free) vs unswizzled j*4 + (row>>1) = 4 banks x 16-way. Reads fetch row
// Dn from position Dn ^ ((Dn>>3)&7) (identical mapping).
__global__ __launch_bounds__(256) void attn_kernel(const bf16_t* __restrict__ qkv,
                                                   const int* __restrict__ toks,
                                                   bf16_t* __restrict__ ctx, int causal) {
  __shared__ __align__(16) bf16_t Qs[QT * 64];
  __shared__ __align__(16) bf16_t Ks[KT * 64];
  __shared__ __align__(16) bf16_t Vs[64 * VPAD];
  __shared__ __align__(16) bf16_t Ps[QT * VPAD];
  __shared__ int Ts[SEQ];
  const int tid = threadIdx.x;
  const int wave = tid >> 6, lane = tid & 63;
  const int lm = lane & 15, lq = lane >> 4;
  // XCD-aware remap: same-(b,h) q-tiles co-locate per XCD (KV L2 reuse).
  const int lin = (int)blockIdx.x + 8 * (int)blockIdx.y;
  const int nxy = 8 * (int)gridDim.y;
  const int nlin = (lin & 7) * (nxy >> 3) + (lin >> 3);
  const int q0 = (nlin & 7) * QT;
  const int bh = nlin >> 3;
  const int b = bh / NHEAD, h = bh % NHEAD;
  const long rowbase = (long)b * SEQ;
  const int LD = 3 * DMODEL;
  const bf16_t* Qg = qkv + (rowbase + q0) * LD + h * DHEAD;
  const bf16_t* Kg = qkv + rowbase * LD + DMODEL + h * DHEAD;
  const bf16_t* Vg = qkv + rowbase * LD + 2 * DMODEL + h * DHEAD;

  Ts[tid] = toks[b * SEQ + tid];
  Ts[tid + 256] = toks[b * SEQ + tid + 256];

#pragma unroll
  for (int r = 0; r < 2; ++r) {
    const int c = r * 256 + tid;
    const int row = c >> 3, c8 = (c & 7) * 8;
    async_load16(Qg + (long)row * LD + c8, &Qs[c * 8]);
  }
  __syncthreads();

  bf16x8 aQ0 = *(const bf16x8*)&Qs[(wave * 16 + lm) * 64 + lq * 8];
  bf16x8 aQ1 = *(const bf16x8*)&Qs[(wave * 16 + lm) * 64 + 32 + lq * 8];

  float m_i[4], l_i[4];
  f32x4 O[4] = {};
#pragma unroll
  for (int r = 0; r < 4; ++r) { m_i[r] = -3.0e38f; l_i[r] = 0.0f; }

  const int s_end = causal ? (q0 + QT) : SEQ;
  for (int s0 = 0; s0 < s_end; s0 += KT) {
    __syncthreads();
#pragma unroll
    for (int r = 0; r < 4; ++r) {
      const int c = r * 256 + tid;
      const int row = c >> 3, c8 = (c & 7) * 8;
      async_load16(Kg + (long)(s0 + row) * LD + c8, &Ks[c * 8]);
    }
#pragma unroll
    for (int r = 0; r < 4; ++r) {
      const int c = r * 256 + tid;
      const int row = c >> 3, c8 = (c & 7) * 8;
      const int sx = c & 7;  // == d>>3 for every d in [c8, c8+8)
      const bf16x8 vv = *(const bf16x8*)(Vg + (long)(s0 + row) * LD + c8);
#pragma unroll
      for (int j = 0; j < 8; ++j) Vs[(c8 + (j ^ sx)) * VPAD + row] = vv[j];
    }
    __syncthreads();

    f32x4 sv[8];
#pragma unroll
    for (int jt = 0; jt < 8; ++jt) {
      const bf16x8 b0 = *(const bf16x8*)&Ks[(jt * 16 + lm) * 64 + lq * 8];
      const bf16x8 b1 = *(const bf16x8*)&Ks[(jt * 16 + lm) * 64 + 32 + lq * 8];
      f32x4 a = {};
      a = __builtin_amdgcn_mfma_f32_16x16x32_bf16(aQ0, b0, a, 0, 0, 0);
      a = __builtin_amdgcn_mfma_f32_16x16x32_bf16(aQ1, b1, a, 0, 0, 0);
      sv[jt] = a;
    }

#pragma unroll
    for (int r = 0; r < 4; ++r) {
      const int qa = q0 + wave * 16 + lq * 4 + r;
      float sr[8];
      float mx = -3.0e38f;
#pragma unroll
      for (int jt = 0; jt < 8; ++jt) {
        const int k = s0 + jt * 16 + lm;
        const float x = sv[jt][r] * 0.125f;
        const bool msk = (Ts[k] == 0) || (causal && (k > qa));
        sr[jt] = msk ? -1.0e18f : x;
        mx = fmaxf(mx, sr[jt]);
      }
#pragma unroll
      for (int o = 1; o < 16; o <<= 1) mx = fmaxf(mx, __shfl_xor(mx, o, 64));
      const float mn = fmaxf(m_i[r], mx);
      const float alpha = __expf(m_i[r] - mn);
      float sum = 0.0f;
#pragma unroll
      for (int jt = 0; jt < 8; ++jt) {
        const float pv = __expf(sr[jt] - mn);
        sr[jt] = pv;
        sum += pv;
      }
#pragma unroll
      for (int o = 1; o < 16; o <<= 1) sum += __shfl_xor(sum, o, 64);
      l_i[r] = l_i[r] * alpha + sum;
      m_i[r] = mn;
#pragma unroll
      for (int jn = 0; jn < 4; ++jn) O[jn][r] *= alpha;
#pragma unroll
      for (int jt = 0; jt < 8; ++jt)
        Ps[(wave * 16 + lq * 4 + r) * VPAD + jt * 16 + lm] = (bf16_t)sr[jt];
    }

#pragma unroll
    for (int kt = 0; kt < 4; ++kt) {
      const bf16x8 aP = *(const bf16x8*)&Ps[(wave * 16 + lm) * VPAD + kt * 32 + lq * 8];
#pragma unroll
      for (int jn = 0; jn < 4; ++jn) {
        const int Dn = jn * 16 + lm;
        const bf16x8 bV =
            *(const bf16x8*)&Vs[(Dn ^ ((Dn >> 3) & 7)) * VPAD + kt * 32 + lq * 8];
        O[jn] = __builtin_amdgcn_mfma_f32_16x16x32_bf16(aP, bV, O[jn], 0, 0, 0);
      }
    }
  }

#pragma unroll
  for (int r = 0; r < 4; ++r) {
    const int q = q0 + wave * 16 + lq * 4 + r;
    const float inv = 1.0f / l_i[r];
#pragma unroll
    for (int jn = 0; jn < 4; ++jn) {
      const int d = jn * 16 + lm;
      ctx[(rowbase + q) * DMODEL + h * DHEAD + d] = (bf16_t)(O[jn][r] * inv);
    }
  }
}

// ---------- LayerNorm (row = 768) ----------
__global__ __launch_bounds__(256) void ln_kernel(const float* __restrict__ X,
                                                 const float* __restrict__ g,
                                                 const float* __restrict__ b,
                                                 bf16_t* __restrict__ outB,
                                                 float* __restrict__ outF) {
  const int row = blockIdx.x, tid = threadIdx.x;
  const float* xr = X + (long)row * DMODEL;
  const float v0 = xr[tid], v1 = xr[tid + 256], v2 = xr[tid + 512];
  __shared__ float r1[4], r2[4];
  const int wv = tid >> 6, ln = tid & 63;
  float s = wsum(v0 + v1 + v2);
  if (ln == 0) r1[wv] = s;
  __syncthreads();
  const float mean = (r1[0] + r1[1] + r1[2] + r1[3]) * (1.0f / DMODEL);
  const float d0 = v0 - mean, d1 = v1 - mean, d2 = v2 - mean;
  float q = wsum(d0 * d0 + d1 * d1 + d2 * d2);
  if (ln == 0) r2[wv] = q;
  __syncthreads();
  const float var = (r2[0] + r2[1] + r2[2] + r2[3]) * (1.0f / DMODEL);
  const float rs = rsqrtf(var + 1e-6f);
  const float y0 = d0 * rs * g[tid] + b[tid];
  const float y1 = d1 * rs * g[tid + 256] + b[tid + 256];
  const float y2 = d2 * rs * g[tid + 512] + b[tid + 512];
  const long base = (long)row * DMODEL;
  if (outB) {
    outB[base + tid] = (bf16_t)y0;
    outB[base + tid + 256] = (bf16_t)y1;
    outB[base + tid + 512] = (bf16_t)y2;
  }
  if (outF) {
    outF[base + tid] = y0;
    outF[base + tid + 256] = y1;
    outF[base + tid + 512] = y2;
  }
}

// ---------- reduce split-K partials + bias + residual, then LayerNorm ----------
// partials p < n1 live at parts + p*pstr; p >= n1 at parts2 + (p-n1)*pstr.
__global__ __launch_bounds__(256) void reduce_ln_kernel(
    const float* __restrict__ parts, const float* __restrict__ parts2,
    long pstr, int np, int n1,
    const float* __restrict__ bias, float* __restrict__ res,
    const float* __restrict__ g, const float* __restrict__ b,
    bf16_t* __restrict__ outB, float* __restrict__ outF) {
  const int row = blockIdx.x, tid = threadIdx.x;
  const long base = (long)row * DMODEL;
  float v0, v1, v2;
  {
    float t0 = res[base + tid] + bias[tid];
    float t1 = res[base + tid + 256] + bias[tid + 256];
    float t2 = res[base + tid + 512] + bias[tid + 512];
    for (int p = 0; p < np; ++p) {
      const float* pp =
          (p < n1 ? parts + (long)p * pstr : parts2 + (long)(p - n1) * pstr) + base;
      t0 += pp[tid];
      t1 += pp[tid + 256];
      t2 += pp[tid + 512];
    }
    v0 = t0; v1 = t1; v2 = t2;
    res[base + tid] = t0;
    res[base + tid + 256] = t1;
    res[base + tid + 512] = t2;
  }
  __shared__ float r1[4], r2[4];
  const int wv = tid >> 6, ln = tid & 63;
  float s = wsum(v0 + v1 + v2);
  if (ln == 0) r1[wv] = s;
  __syncthreads();
  const float mean = (r1[0] + r1[1] + r1[2] + r1[3]) * (1.0f / DMODEL);
  const float d0 = v0 - mean, d1 = v1 - mean, d2 = v2 - mean;
  float q = wsum(d0 * d0 + d1 * d1 + d2 * d2);
  if (ln == 0) r2[wv] = q;
  __syncthreads();
  const float var = (r2[0] + r2[1] + r2[2] + r2[3]) * (1.0f / DMODEL);
  const float rs = rsqrtf(var + 1e-6f);
  const float y0 = d0 * rs * g[tid] + b[tid];
  const float y1 = d1 * rs * g[tid + 256] + b[tid + 256];
  const float y2 = d2 * rs * g[tid + 512] + b[tid + 512];
  if (outB) {
    outB[base + tid] = (bf16_t)y0;
    outB[base + tid + 256] = (bf16_t)y1;
    outB[base + tid + 512] = (bf16_t)y2;
  }
  if (outF) {
    outF[base + tid] = y0;
    outF[base + tid + 256] = y1;
    outF[base + tid + 512] = y2;
  }
}

// ---------- reduce split-K partials + bias -> strided bf16 (CA-q into qkv) ----------
__global__ __launch_bounds__(256) void reduce_cvtq_kernel(
    const float* __restrict__ parts, const float* __restrict__ parts2,
    long pstr, int np, int n1,
    const float* __restrict__ bias, bf16_t* __restrict__ o) {
  const int row = blockIdx.x, tid = threadIdx.x;
  const long base = (long)row * DMODEL;
  const long ob = (long)row * 3 * DMODEL;
#pragma unroll
  for (int c = 0; c < 3; ++c) {
    const int col = tid + c * 256;
    float t = bias[col];
    for (int p = 0; p < np; ++p) {
      const float* pp =
          (p < n1 ? parts + (long)p * pstr : parts2 + (long)(p - n1) * pstr);
      t += pp[base + col];
    }
    o[ob + col] = (bf16_t)t;
  }
}

// ---------- embedding * sqrt(D) + sinusoidal PE ----------
__global__ __launch_bounds__(256) void emb_kernel(const int* __restrict__ tgt,
                                                  const float* __restrict__ tab,
                                                  float* __restrict__ res) {
  const int row = blockIdx.x;
  const int t = row & (SEQ - 1);
  const long tok = tgt[row];
  const float* er = tab + tok * DMODEL;
  float* orow = res + (long)row * DMODEL;
  const float c1 = -9.210340371976184f / 768.0f;
  for (int c = threadIdx.x; c < DMODEL; c += 256) {
    const float e = er[c] * 27.712812921102035f;
    const float div = expf((float)(c & ~1) * c1);
    const float ang = (float)t * div;
    const float pe = (c & 1) ? cosf(ang) : sinf(ang);
    orow[c] = e + pe;
  }
}

// ---------- f32 -> bf16 convert (n4 = n/4) ----------
__global__ __launch_bounds__(256) void cvt_kernel(const float* __restrict__ in,
                                                  bf16_t* __restrict__ o, int n4) {
  const int i = blockIdx.x * 256 + threadIdx.x;
  if (i < n4) {
    const float4 v = ((const float4*)in)[i];
    bf16x4 r = {(bf16_t)v.x, (bf16_t)v.y, (bf16_t)v.z, (bf16_t)v.w};
    ((bf16x4*)o)[i] = r;
  }
}

// ---------- host ----------
extern "C" void kernel_launch(void* const* d_in, const int* in_sizes, int n_in,
                              void* d_out, int out_size, void* d_ws, size_t ws_size,
                              hipStream_t stream) {
  (void)in_sizes; (void)n_in; (void)out_size; (void)ws_size;
  const int* tgt = (const int*)d_in[0];
  const int* srct = (const int*)d_in[1];
  const float* memb = (const float*)d_in[2];
  const float* embt = (const float*)d_in[3];
  const float* sa_w = (const float*)d_in[4];
  const float* sa_b = (const float*)d_in[5];
  const float* ca_w = (const float*)d_in[6];
  const float* ca_b = (const float*)d_in[7];
  const float* ln_g = (const float*)d_in[8];
  const float* ln_b = (const float*)d_in[9];
  const float* ff_w1 = (const float*)d_in[10];
  const float* ff_b1 = (const float*)d_in[11];
  const float* ff_w2 = (const float*)d_in[12];
  const float* ff_b2 = (const float*)d_in[13];
  const float* out_g = (const float*)d_in[14];
  const float* out_b = (const float*)d_in[15];
  float* out = (float*)d_out;

  char* wsb = (char*)d_ws;
  size_t off = 0;
  auto alloc = [&](size_t bytes) -> void* {
    void* pp = wsb + off;
    off = (off + bytes + 255) & ~(size_t)255;
    return pp;
  };
  // Allocation ORDER/SIZES load-bearing:
  //  - partials p=0..3 live at parts + p*PSTR: parts(2 slots) then the
  //    contiguous xb+qkvb region (= exactly 2 more slots). xb/qkvb are DEAD
  //    at every GEMM using p>=2 there (LN outputs live in ctxb, never xb).
  //  - partials p=4.. (SA/CA-out ksplit=6) and CA-q's p=2,3 use ffh
  //    (= exactly 2 slots; dead outside the FFN1->FFN2 window).
  float* res = (float*)alloc((size_t)MROWS * DMODEL * 4);
  float* parts = (float*)alloc((size_t)2 * MROWS * DMODEL * 4);  // partials 0..1
  bf16_t* xb = (bf16_t*)alloc((size_t)MROWS * DMODEL * 2);       // partial 2 space
  bf16_t* qkvb = (bf16_t*)alloc((size_t)MROWS * 3 * DMODEL * 2); // partial 2/3 space
  bf16_t* ctxb = (bf16_t*)alloc((size_t)MROWS * DMODEL * 2);
  bf16_t* membb = (bf16_t*)alloc((size_t)MROWS * DMODEL * 2);
  bf16_t* ffh = (bf16_t*)alloc((size_t)MROWS * DFFN * 2);        // partials 4..5 space
  bf16_t* wA = (bf16_t*)alloc((size_t)4 * DMODEL * DMODEL * 2);
  bf16_t* wF1 = (bf16_t*)alloc((size_t)DFFN * DMODEL * 2);
  bf16_t* wF2 = (bf16_t*)alloc((size_t)DFFN * DMODEL * 2);
  (void)xb;
  float* partsF = (float*)ffh;  // 2 partial slots overlay

  const long PSTR = (long)MROWS * DMODEL;

  auto gemm = [&](const bf16_t* A, const bf16_t* Bm, const float* bias,
                  float* oF, float* oF2, int zext, bf16_t* oB, int M, int N, int K,
                  int lda, int ldb, int ldc, int act, int ksplit) {
    GP p{A, Bm, bias, oF, oF2, oB, M, N, K, lda, ldb, ldc, PSTR, act, ksplit, zext};
    dim3 g((unsigned)(M / 128), (unsigned)(N / 128), (unsigned)ksplit);
    gemm128<<<g, 256, 0, stream>>>(p);
  };

  const long WSZ = (long)DMODEL * DMODEL;

  emb_kernel<<<MROWS, 256, 0, stream>>>(tgt, embt, res);
  cvt_kernel<<<(MROWS * DMODEL / 4 + 255) / 256, 256, 0, stream>>>(memb, membb,
                                                                   MROWS * DMODEL / 4);
  ln_kernel<<<MROWS, 256, 0, stream>>>(res, ln_g, ln_b, ctxb, nullptr);

  for (int l = 0; l < NLAYER; ++l) {
    const float* saw = sa_w + (long)l * 4 * WSZ;
    const float* sab = sa_b + (long)l * 4 * DMODEL;
    const float* caw = ca_w + (long)l * 4 * WSZ;
    const float* cab = ca_b + (long)l * 4 * DMODEL;

    // ======== self-attention ========   (ctxb = ln1)
    cvt_kernel<<<(int)((WSZ + 255) / 256), 256, 0, stream>>>(saw, wA, (int)WSZ);
    gemm(ctxb, wA, sab, nullptr, nullptr, 4, qkvb, MROWS, 3 * DMODEL, DMODEL,
         DMODEL, DMODEL, 3 * DMODEL, 0, 1);
    attn_kernel<<<dim3(SEQ / QT, BATCH * NHEAD), 256, 0, stream>>>(qkvb, tgt, ctxb, 1);
    // SA-out: ksplit=6 (partials: parts0,1 + xb/qkvb 2,3 + ffh 4,5)
    gemm(ctxb, wA + 3 * WSZ, nullptr, parts, partsF, 4, nullptr, MROWS, DMODEL, DMODEL,
         DMODEL, DMODEL, DMODEL, 0, 6);
    reduce_ln_kernel<<<MROWS, 256, 0, stream>>>(parts, partsF, PSTR, 6, 4,
                                                sab + 3 * DMODEL, res,
                                                ln_g + (l * 3 + 1) * DMODEL,
                                                ln_b + (l * 3 + 1) * DMODEL, ctxb, nullptr);

    // ======== cross-attention ========  (ctxb = ln2)
    cvt_kernel<<<(int)((WSZ + 255) / 256), 256, 0, stream>>>(caw, wA, (int)WSZ);
    // CA-q: ksplit=4 with partials {parts0,1, ffh0,1} (NOT qkvb: its reduce
    // writes qkvb, which would race with a qkvb-aliased partial)
    gemm(ctxb, wA, nullptr, parts, partsF, 2, nullptr, MROWS, DMODEL, DMODEL,
         DMODEL, DMODEL, DMODEL, 0, 4);
    reduce_cvtq_kernel<<<MROWS, 256, 0, stream>>>(parts, partsF, PSTR, 4, 2, cab, qkvb);
    gemm(membb, wA + WSZ, cab + DMODEL, nullptr, nullptr, 4, qkvb + DMODEL, MROWS,
         2 * DMODEL, DMODEL, DMODEL, DMODEL, 3 * DMODEL, 0, 1);
    attn_kernel<<<dim3(SEQ / QT, BATCH * NHEAD), 256, 0, stream>>>(qkvb, srct, ctxb, 0);
    // CA-out: ksplit=6
    gemm(ctxb, wA + 3 * WSZ, nullptr, parts, partsF, 4, nullptr, MROWS, DMODEL, DMODEL,
         DMODEL, DMODEL, DMODEL, 0, 6);
    reduce_ln_kernel<<<MROWS, 256, 0, stream>>>(parts, partsF, PSTR, 6, 4,
                                                cab + 3 * DMODEL, res,
                                                ln_g + (l * 3 + 2) * DMODEL,
                                                ln_b + (l * 3 + 2) * DMODEL, ctxb, nullptr);

    // ======== FFN ========  (ctxb = ln3)
    cvt_kernel<<<(int)((DFFN * (long)DMODEL / 4 + 255) / 256), 256, 0, stream>>>(
        ff_w1 + (long)l * DFFN * DMODEL, wF1, (int)(DFFN * (long)DMODEL / 4));
    cvt_kernel<<<(int)((DFFN * (long)DMODEL / 4 + 255) / 256), 256, 0, stream>>>(
        ff_w2 + (long)l * DFFN * DMODEL, wF2, (int)(DFFN * (long)DMODEL / 4));
    gemm(ctxb, wF1, ff_b1 + (long)l * DFFN, nullptr, nullptr, 4, ffh, MROWS, DFFN,
         DMODEL, DMODEL, DMODEL, DFFN, 1, 1);
    // FFN2: ksplit=4 (ffh is the INPUT here -> only parts0,1 + xb/qkvb usable)
    gemm(ffh, wF2, nullptr, parts, nullptr, 4, nullptr, MROWS, DMODEL, DFFN,
         DFFN, DFFN, DMODEL, 0, 4);
    if (l < NLAYER - 1) {
      reduce_ln_kernel<<<MROWS, 256, 0, stream>>>(parts, nullptr, PSTR, 4, 4,
                                                  ff_b2 + (long)l * DMODEL, res,
                                                  ln_g + ((l + 1) * 3) * DMODEL,
                                                  ln_b + ((l + 1) * 3) * DMODEL, ctxb, nullptr);
    } else {
      reduce_ln_kernel<<<MROWS, 256, 0, stream>>>(parts, nullptr, PSTR, 4, 4,
                                                  ff_b2 + (long)l * DMODEL, res,
                                                  out_g, out_b, nullptr, out);
    }
  }
}

// Round 9
// 2088.806 us; speedup vs baseline: 1.0572x; 1.0572x over previous
//
#include <hip/hip_runtime.h>
#include <math.h>
#include <stdint.h>

typedef __bf16 bf16_t;
typedef __bf16 bf16x8 __attribute__((ext_vector_type(8)));
typedef __bf16 bf16x4 __attribute__((ext_vector_type(4)));
typedef float f32x4 __attribute__((ext_vector_type(4)));

#define NLAYER 6
#define DMODEL 768
#define NHEAD 12
#define DHEAD 64
#define SEQ 512
#define BATCH 8
#define MROWS 4096 /* BATCH*SEQ */
#define DFFN 3072

// ---------- helpers ----------

__device__ inline void async_load16(const void* g, void* lds) {
  const __attribute__((address_space(1))) void* gp =
      (const __attribute__((address_space(1))) void*)(uintptr_t)g;
  __attribute__((address_space(3))) void* lp =
      (__attribute__((address_space(3))) void*)(uint32_t)(uintptr_t)lds;
  __builtin_amdgcn_global_load_lds(gp, lp, 16, 0, 0);
}

#define VMCNT(n) __builtin_amdgcn_s_waitcnt(0x0F70 | (n))
#define LGKM0 __builtin_amdgcn_s_waitcnt(0xC07F) /* lgkmcnt(0) only */

__device__ inline float wsum(float v) {
#pragma unroll
  for (int o = 32; o > 0; o >>= 1) v += __shfl_xor(v, o, 64);
  return v;
}

__device__ inline float gelu_f(float x) {
  // 0.5x(1+tanh(u)) == x / (1 + exp(-2u)); hardware v_exp_f32 path
  const float u = x + 0.044715f * x * x * x;
  return x / (1.0f + __expf(-1.5957691216057308f * u));
}

struct GP {
  const bf16_t* A;
  const bf16_t* B;
  const float* bias;   // [N] or null (ignored when ksplit>1)
  float* outF;         // f32 out (partial base when ksplit>1)
  bf16_t* outB;        // bf16 out or null
  int M, N, K;
  int lda, ldb, ldc;
  long pstride;  // partial-buffer stride (elements) for ksplit>1
  int act;       // 1 = gelu
  int ksplit;
};

// ---------- 128x128 GEMM (r6 proven config: best total 2058us) ----------
// Triple-buffered staging (48KB LDS, 3 blocks/CU): vmcnt(8) waits only on
// loads issued TWO K-steps ago. Conflict-free LDS swizzle (BANK_CONFLICT=0,
// HW-verified). LDS-bounce coalesced epilogue (WRITE_SIZE == ideal).
// NO XCD remap (working sets are L3-fit; swizzle measured-negative there).
__global__ __launch_bounds__(256) void gemm128(GP p) {
  __shared__ __align__(16) char smem[49152];
  bf16_t* As = (bf16_t*)smem;            // [3][128*32]
  bf16_t* Bs = (bf16_t*)(smem + 24576);  // [3][128*32]
  const int tid = threadIdx.x;
  const int wave = tid >> 6, lane = tid & 63;
  const int wr = wave >> 1, wc = wave & 1;
  const int lrow = lane & 15, kq = lane >> 4;
  const int swz = (kq ^ ((lrow >> 1) & 3)) * 8;  // read slot (elements)
  const int sr = tid >> 2;
  const int scs = ((tid & 3) ^ ((tid >> 3) & 3)) << 3;  // inv-swizzled src col
  const int m0 = blockIdx.x * 128;
  const int n0 = blockIdx.y * 128;
  const int zs = (int)blockIdx.z;

  const int kc = p.K / p.ksplit;
  const int kstart = zs * kc;
  const int kend = kstart + kc;

  auto stage = [&](int k0, int buf) {
#pragma unroll
    for (int r = 0; r < 2; ++r)
      async_load16(p.A + (long)(m0 + r * 64 + sr) * p.lda + (k0 + scs),
                   As + buf * 4096 + (r * 64 + wave * 16) * 32);
#pragma unroll
    for (int r = 0; r < 2; ++r)
      async_load16(p.B + (long)(n0 + r * 64 + sr) * p.ldb + (k0 + scs),
                   Bs + buf * 4096 + (r * 64 + wave * 16) * 32);
  };

  f32x4 acc[4][4] = {};
  stage(kstart, 0);
  if (kstart + 32 < kend) stage(kstart + 32, 1);
  int cur = 0, nxt = 1, fut = 2;

  for (int k0 = kstart; k0 < kend; k0 += 32) {
    if (k0 + 64 < kend) {
      stage(k0 + 64, fut);  // fut's last readers finished 2 barriers ago
      VMCNT(8);             // cur's 4 loads (issued 2 iters ago) landed
    } else if (k0 + 32 < kend) {
      VMCNT(4);
    } else {
      VMCNT(0);
    }
    __builtin_amdgcn_s_barrier();

    const int cb = cur * 4096;
    bf16x8 af[4], bfr[4];
#pragma unroll
    for (int i = 0; i < 4; ++i)
      af[i] = *(const bf16x8*)&As[cb + (wr * 64 + i * 16 + lrow) * 32 + swz];
#pragma unroll
    for (int j = 0; j < 4; ++j)
      bfr[j] = *(const bf16x8*)&Bs[cb + (wc * 64 + j * 16 + lrow) * 32 + swz];
#pragma unroll
    for (int i = 0; i < 4; ++i)
#pragma unroll
      for (int j = 0; j < 4; ++j)
        acc[i][j] = __builtin_amdgcn_mfma_f32_16x16x32_bf16(af[i], bfr[j], acc[i][j], 0, 0, 0);

    __builtin_amdgcn_s_barrier();  // all waves done reading cur before reuse
    const int t = cur; cur = nxt; nxt = fut; fut = t;
  }

  // ---- epilogue: LDS-bounce coalesced stores (staging LDS is dead) ----
  const int colbase = n0 + wc * 64;
  const int lc = lrow;  // lane & 15
  float* eb = (float*)(smem + wave * 4608);  // per-wave 4.6KB private

  if (p.ksplit > 1) {
    float* po = p.outF + (long)zs * p.pstride;
#pragma unroll
    for (int i = 0; i < 4; ++i) {
      const int rg0 = m0 + wr * 64 + i * 16;
#pragma unroll
      for (int j = 0; j < 4; ++j)
#pragma unroll
        for (int r = 0; r < 4; ++r)
          eb[(kq * 4 + r) * 68 + j * 16 + lc] = acc[i][j][r];
      LGKM0;
#pragma unroll
      for (int q = 0; q < 4; ++q) {
        const int row = q * 4 + kq;
        const f32x4 v = *(const f32x4*)&eb[row * 68 + lc * 4];
        *(f32x4*)&po[(long)(rg0 + row) * p.ldc + colbase + lc * 4] = v;
      }
      LGKM0;  // reads retired before next i overwrites
    }
  } else {
    float bs[4] = {0.f, 0.f, 0.f, 0.f};
    if (p.bias) {
#pragma unroll
      for (int j = 0; j < 4; ++j) bs[j] = p.bias[colbase + j * 16 + lc];
    }
    bf16_t* bh = (bf16_t*)eb;  // stride 72 (144B = 9x16B, quad-rotating)
    const int l8r = lane >> 3, l8c = lane & 7;
#pragma unroll
    for (int i = 0; i < 4; ++i) {
      const int rg0 = m0 + wr * 64 + i * 16;
#pragma unroll
      for (int j = 0; j < 4; ++j)
#pragma unroll
        for (int r = 0; r < 4; ++r) {
          float y = acc[i][j][r] + bs[j];
          if (p.act) y = gelu_f(y);
          bh[(kq * 4 + r) * 72 + j * 16 + lc] = (bf16_t)y;
        }
      LGKM0;
      if (p.outB) {
#pragma unroll
        for (int q = 0; q < 2; ++q) {
          const int row = q * 8 + l8r;
          const bf16x8 v = *(const bf16x8*)&bh[row * 72 + l8c * 8];
          *(bf16x8*)&p.outB[(long)(rg0 + row) * p.ldc + colbase + l8c * 8] = v;
        }
      }
      LGKM0;
    }
  }
}

// ---------- fused flash attention ----------
#define QT 64
#define KT 128
#define VPAD 136

// V-transpose store swizzle (kept from r8, mapping HW-validated): VALUE of
// row d (= c8+j) is stored at position c8 + (j ^ sx), sx = d>>3 within the
// 8-row group. Write banks 4*(j^sx)+row/2 = 8 distinct x 2-way (free) vs
// unswizzled 16-way. Reads fetch row Dn from Dn ^ ((Dn>>3)&7).
// Grid mapping: NATURAL order (r8's XCD remap co-located unequal-work
// causal q-tiles per XCD -> imbalance; reverted).
__global__ __launch_bounds__(256) void attn_kernel(const bf16_t* __restrict__ qkv,
                                                   const int* __restrict__ toks,
                                                   bf16_t* __restrict__ ctx, int causal) {
  __shared__ __align__(16) bf16_t Qs[QT * 64];
  __shared__ __align__(16) bf16_t Ks[KT * 64];
  __shared__ __align__(16) bf16_t Vs[64 * VPAD];
  __shared__ __align__(16) bf16_t Ps[QT * VPAD];
  __shared__ int Ts[SEQ];
  const int tid = threadIdx.x;
  const int wave = tid >> 6, lane = tid & 63;
  const int lm = lane & 15, lq = lane >> 4;
  const int q0 = blockIdx.x * QT;
  const int bh = blockIdx.y;
  const int b = bh / NHEAD, h = bh % NHEAD;
  const long rowbase = (long)b * SEQ;
  const int LD = 3 * DMODEL;
  const bf16_t* Qg = qkv + (rowbase + q0) * LD + h * DHEAD;
  const bf16_t* Kg = qkv + rowbase * LD + DMODEL + h * DHEAD;
  const bf16_t* Vg = qkv + rowbase * LD + 2 * DMODEL + h * DHEAD;

  Ts[tid] = toks[b * SEQ + tid];
  Ts[tid + 256] = toks[b * SEQ + tid + 256];

#pragma unroll
  for (int r = 0; r < 2; ++r) {
    const int c = r * 256 + tid;
    const int row = c >> 3, c8 = (c & 7) * 8;
    async_load16(Qg + (long)row * LD + c8, &Qs[c * 8]);
  }
  __syncthreads();

  bf16x8 aQ0 = *(const bf16x8*)&Qs[(wave * 16 + lm) * 64 + lq * 8];
  bf16x8 aQ1 = *(const bf16x8*)&Qs[(wave * 16 + lm) * 64 + 32 + lq * 8];

  float m_i[4], l_i[4];
  f32x4 O[4] = {};
#pragma unroll
  for (int r = 0; r < 4; ++r) { m_i[r] = -3.0e38f; l_i[r] = 0.0f; }

  const int s_end = causal ? (q0 + QT) : SEQ;
  for (int s0 = 0; s0 < s_end; s0 += KT) {
    __syncthreads();
#pragma unroll
    for (int r = 0; r < 4; ++r) {
      const int c = r * 256 + tid;
      const int row = c >> 3, c8 = (c & 7) * 8;
      async_load16(Kg + (long)(s0 + row) * LD + c8, &Ks[c * 8]);
    }
#pragma unroll
    for (int r = 0; r < 4; ++r) {
      const int c = r * 256 + tid;
      const int row = c >> 3, c8 = (c & 7) * 8;
      const int sx = c & 7;  // == d>>3 for every d in [c8, c8+8)
      const bf16x8 vv = *(const bf16x8*)(Vg + (long)(s0 + row) * LD + c8);
#pragma unroll
      for (int j = 0; j < 8; ++j) Vs[(c8 + (j ^ sx)) * VPAD + row] = vv[j];
    }
    __syncthreads();

    f32x4 sv[8];
#pragma unroll
    for (int jt = 0; jt < 8; ++jt) {
      const bf16x8 b0 = *(const bf16x8*)&Ks[(jt * 16 + lm) * 64 + lq * 8];
      const bf16x8 b1 = *(const bf16x8*)&Ks[(jt * 16 + lm) * 64 + 32 + lq * 8];
      f32x4 a = {};
      a = __builtin_amdgcn_mfma_f32_16x16x32_bf16(aQ0, b0, a, 0, 0, 0);
      a = __builtin_amdgcn_mfma_f32_16x16x32_bf16(aQ1, b1, a, 0, 0, 0);
      sv[jt] = a;
    }

#pragma unroll
    for (int r = 0; r < 4; ++r) {
      const int qa = q0 + wave * 16 + lq * 4 + r;
      float sr[8];
      float mx = -3.0e38f;
#pragma unroll
      for (int jt = 0; jt < 8; ++jt) {
        const int k = s0 + jt * 16 + lm;
        const float x = sv[jt][r] * 0.125f;
        const bool msk = (Ts[k] == 0) || (causal && (k > qa));
        sr[jt] = msk ? -1.0e18f : x;
        mx = fmaxf(mx, sr[jt]);
      }
#pragma unroll
      for (int o = 1; o < 16; o <<= 1) mx = fmaxf(mx, __shfl_xor(mx, o, 64));
      const float mn = fmaxf(m_i[r], mx);
      const float alpha = __expf(m_i[r] - mn);
      float sum = 0.0f;
#pragma unroll
      for (int jt = 0; jt < 8; ++jt) {
        const float pv = __expf(sr[jt] - mn);
        sr[jt] = pv;
        sum += pv;
      }
#pragma unroll
      for (int o = 1; o < 16; o <<= 1) sum += __shfl_xor(sum, o, 64);
      l_i[r] = l_i[r] * alpha + sum;
      m_i[r] = mn;
#pragma unroll
      for (int jn = 0; jn < 4; ++jn) O[jn][r] *= alpha;
#pragma unroll
      for (int jt = 0; jt < 8; ++jt)
        Ps[(wave * 16 + lq * 4 + r) * VPAD + jt * 16 + lm] = (bf16_t)sr[jt];
    }

#pragma unroll
    for (int kt = 0; kt < 4; ++kt) {
      const bf16x8 aP = *(const bf16x8*)&Ps[(wave * 16 + lm) * VPAD + kt * 32 + lq * 8];
#pragma unroll
      for (int jn = 0; jn < 4; ++jn) {
        const int Dn = jn * 16 + lm;
        const bf16x8 bV =
            *(const bf16x8*)&Vs[(Dn ^ ((Dn >> 3) & 7)) * VPAD + kt * 32 + lq * 8];
        O[jn] = __builtin_amdgcn_mfma_f32_16x16x32_bf16(aP, bV, O[jn], 0, 0, 0);
      }
    }
  }

#pragma unroll
  for (int r = 0; r < 4; ++r) {
    const int q = q0 + wave * 16 + lq * 4 + r;
    const float inv = 1.0f / l_i[r];
#pragma unroll
    for (int jn = 0; jn < 4; ++jn) {
      const int d = jn * 16 + lm;
      ctx[(rowbase + q) * DMODEL + h * DHEAD + d] = (bf16_t)(O[jn][r] * inv);
    }
  }
}

// ---------- LayerNorm (row = 768) ----------
__global__ __launch_bounds__(256) void ln_kernel(const float* __restrict__ X,
                                                 const float* __restrict__ g,
                                                 const float* __restrict__ b,
                                                 bf16_t* __restrict__ outB,
                                                 float* __restrict__ outF) {
  const int row = blockIdx.x, tid = threadIdx.x;
  const float* xr = X + (long)row * DMODEL;
  const float v0 = xr[tid], v1 = xr[tid + 256], v2 = xr[tid + 512];
  __shared__ float r1[4], r2[4];
  const int wv = tid >> 6, ln = tid & 63;
  float s = wsum(v0 + v1 + v2);
  if (ln == 0) r1[wv] = s;
  __syncthreads();
  const float mean = (r1[0] + r1[1] + r1[2] + r1[3]) * (1.0f / DMODEL);
  const float d0 = v0 - mean, d1 = v1 - mean, d2 = v2 - mean;
  float q = wsum(d0 * d0 + d1 * d1 + d2 * d2);
  if (ln == 0) r2[wv] = q;
  __syncthreads();
  const float var = (r2[0] + r2[1] + r2[2] + r2[3]) * (1.0f / DMODEL);
  const float rs = rsqrtf(var + 1e-6f);
  const float y0 = d0 * rs * g[tid] + b[tid];
  const float y1 = d1 * rs * g[tid + 256] + b[tid + 256];
  const float y2 = d2 * rs * g[tid + 512] + b[tid + 512];
  const long base = (long)row * DMODEL;
  if (outB) {
    outB[base + tid] = (bf16_t)y0;
    outB[base + tid + 256] = (bf16_t)y1;
    outB[base + tid + 512] = (bf16_t)y2;
  }
  if (outF) {
    outF[base + tid] = y0;
    outF[base + tid + 256] = y1;
    outF[base + tid + 512] = y2;
  }
}

// ---------- reduce split-K partials + bias + residual, then LayerNorm ----------
__global__ __launch_bounds__(256) void reduce_ln_kernel(
    const float* __restrict__ parts, long pstr, int np,
    const float* __restrict__ bias, float* __restrict__ res,
    const float* __restrict__ g, const float* __restrict__ b,
    bf16_t* __restrict__ outB, float* __restrict__ outF) {
  const int row = blockIdx.x, tid = threadIdx.x;
  const long base = (long)row * DMODEL;
  float v0, v1, v2;
  {
    float t0 = res[base + tid] + bias[tid];
    float t1 = res[base + tid + 256] + bias[tid + 256];
    float t2 = res[base + tid + 512] + bias[tid + 512];
    for (int p = 0; p < np; ++p) {
      const float* pp = parts + p * pstr + base;
      t0 += pp[tid];
      t1 += pp[tid + 256];
      t2 += pp[tid + 512];
    }
    v0 = t0; v1 = t1; v2 = t2;
    res[base + tid] = t0;
    res[base + tid + 256] = t1;
    res[base + tid + 512] = t2;
  }
  __shared__ float r1[4], r2[4];
  const int wv = tid >> 6, ln = tid & 63;
  float s = wsum(v0 + v1 + v2);
  if (ln == 0) r1[wv] = s;
  __syncthreads();
  const float mean = (r1[0] + r1[1] + r1[2] + r1[3]) * (1.0f / DMODEL);
  const float d0 = v0 - mean, d1 = v1 - mean, d2 = v2 - mean;
  float q = wsum(d0 * d0 + d1 * d1 + d2 * d2);
  if (ln == 0) r2[wv] = q;
  __syncthreads();
  const float var = (r2[0] + r2[1] + r2[2] + r2[3]) * (1.0f / DMODEL);
  const float rs = rsqrtf(var + 1e-6f);
  const float y0 = d0 * rs * g[tid] + b[tid];
  const float y1 = d1 * rs * g[tid + 256] + b[tid + 256];
  const float y2 = d2 * rs * g[tid + 512] + b[tid + 512];
  if (outB) {
    outB[base + tid] = (bf16_t)y0;
    outB[base + tid + 256] = (bf16_t)y1;
    outB[base + tid + 512] = (bf16_t)y2;
  }
  if (outF) {
    outF[base + tid] = y0;
    outF[base + tid + 256] = y1;
    outF[base + tid + 512] = y2;
  }
}

// ---------- reduce split-K partials + bias -> strided bf16 (CA-q into qkv) ----------
__global__ __launch_bounds__(256) void reduce_cvtq_kernel(
    const float* __restrict__ parts, long pstr, int np,
    const float* __restrict__ bias, bf16_t* __restrict__ o) {
  const int row = blockIdx.x, tid = threadIdx.x;
  const long base = (long)row * DMODEL;
  const long ob = (long)row * 3 * DMODEL;
#pragma unroll
  for (int c = 0; c < 3; ++c) {
    const int col = tid + c * 256;
    float t = bias[col];
    for (int p = 0; p < np; ++p) t += parts[p * pstr + base + col];
    o[ob + col] = (bf16_t)t;
  }
}

// ---------- embedding * sqrt(D) + sinusoidal PE ----------
__global__ __launch_bounds__(256) void emb_kernel(const int* __restrict__ tgt,
                                                  const float* __restrict__ tab,
                                                  float* __restrict__ res) {
  const int row = blockIdx.x;
  const int t = row & (SEQ - 1);
  const long tok = tgt[row];
  const float* er = tab + tok * DMODEL;
  float* orow = res + (long)row * DMODEL;
  const float c1 = -9.210340371976184f / 768.0f;
  for (int c = threadIdx.x; c < DMODEL; c += 256) {
    const float e = er[c] * 27.712812921102035f;
    const float div = expf((float)(c & ~1) * c1);
    const float ang = (float)t * div;
    const float pe = (c & 1) ? cosf(ang) : sinf(ang);
    orow[c] = e + pe;
  }
}

// ---------- f32 -> bf16 convert (n4 = n/4) ----------
__global__ __launch_bounds__(256) void cvt_kernel(const float* __restrict__ in,
                                                  bf16_t* __restrict__ o, int n4) {
  const int i = blockIdx.x * 256 + threadIdx.x;
  if (i < n4) {
    const float4 v = ((const float4*)in)[i];
    bf16x4 r = {(bf16_t)v.x, (bf16_t)v.y, (bf16_t)v.z, (bf16_t)v.w};
    ((bf16x4*)o)[i] = r;
  }
}

// ---------- host ----------
extern "C" void kernel_launch(void* const* d_in, const int* in_sizes, int n_in,
                              void* d_out, int out_size, void* d_ws, size_t ws_size,
                              hipStream_t stream) {
  (void)in_sizes; (void)n_in; (void)out_size; (void)ws_size;
  const int* tgt = (const int*)d_in[0];
  const int* srct = (const int*)d_in[1];
  const float* memb = (const float*)d_in[2];
  const float* embt = (const float*)d_in[3];
  const float* sa_w = (const float*)d_in[4];
  const float* sa_b = (const float*)d_in[5];
  const float* ca_w = (const float*)d_in[6];
  const float* ca_b = (const float*)d_in[7];
  const float* ln_g = (const float*)d_in[8];
  const float* ln_b = (const float*)d_in[9];
  const float* ff_w1 = (const float*)d_in[10];
  const float* ff_b1 = (const float*)d_in[11];
  const float* ff_w2 = (const float*)d_in[12];
  const float* ff_b2 = (const float*)d_in[13];
  const float* out_g = (const float*)d_in[14];
  const float* out_b = (const float*)d_in[15];
  float* out = (float*)d_out;

  char* wsb = (char*)d_ws;
  size_t off = 0;
  auto alloc = [&](size_t bytes) -> void* {
    void* pp = wsb + off;
    off = (off + bytes + 255) & ~(size_t)255;
    return pp;
  };
  // Allocation ORDER/SIZES load-bearing: ksplit=4 partials span
  // parts(2*PSTR) + xb + qkvb exactly (xb+qkvb are DEAD at every ksplit=4
  // GEMM: all LN outputs live in ctxb, never xb).
  float* res = (float*)alloc((size_t)MROWS * DMODEL * 4);
  float* parts = (float*)alloc((size_t)2 * MROWS * DMODEL * 4);  // partials 0..1
  bf16_t* xb = (bf16_t*)alloc((size_t)MROWS * DMODEL * 2);       // partial 2 space
  bf16_t* qkvb = (bf16_t*)alloc((size_t)MROWS * 3 * DMODEL * 2); // partial 2/3 space
  bf16_t* ctxb = (bf16_t*)alloc((size_t)MROWS * DMODEL * 2);
  bf16_t* membb = (bf16_t*)alloc((size_t)MROWS * DMODEL * 2);
  bf16_t* ffh = (bf16_t*)alloc((size_t)MROWS * DFFN * 2);
  bf16_t* wA = (bf16_t*)alloc((size_t)4 * DMODEL * DMODEL * 2);
  bf16_t* wF1 = (bf16_t*)alloc((size_t)DFFN * DMODEL * 2);
  bf16_t* wF2 = (bf16_t*)alloc((size_t)DFFN * DMODEL * 2);
  (void)xb;

  const long PSTR = (long)MROWS * DMODEL;

  auto gemm = [&](const bf16_t* A, const bf16_t* Bm, const float* bias,
                  float* oF, bf16_t* oB, int M, int N, int K,
                  int lda, int ldb, int ldc, int act, int ksplit) {
    GP p{A, Bm, bias, oF, oB, M, N, K, lda, ldb, ldc, PSTR, act, ksplit};
    dim3 g((unsigned)(M / 128), (unsigned)(N / 128), (unsigned)ksplit);
    gemm128<<<g, 256, 0, stream>>>(p);
  };

  const long WSZ = (long)DMODEL * DMODEL;

  emb_kernel<<<MROWS, 256, 0, stream>>>(tgt, embt, res);
  cvt_kernel<<<(MROWS * DMODEL / 4 + 255) / 256, 256, 0, stream>>>(memb, membb,
                                                                   MROWS * DMODEL / 4);
  ln_kernel<<<MROWS, 256, 0, stream>>>(res, ln_g, ln_b, ctxb, nullptr);

  for (int l = 0; l < NLAYER; ++l) {
    const float* saw = sa_w + (long)l * 4 * WSZ;
    const float* sab = sa_b + (long)l * 4 * DMODEL;
    const float* caw = ca_w + (long)l * 4 * WSZ;
    const float* cab = ca_b + (long)l * 4 * DMODEL;

    // ======== self-attention ========   (ctxb = ln1)
    cvt_kernel<<<(int)((WSZ + 255) / 256), 256, 0, stream>>>(saw, wA, (int)WSZ);
    gemm(ctxb, wA, sab, nullptr, qkvb, MROWS, 3 * DMODEL, DMODEL,
         DMODEL, DMODEL, 3 * DMODEL, 0, 1);
    attn_kernel<<<dim3(SEQ / QT, BATCH * NHEAD), 256, 0, stream>>>(qkvb, tgt, ctxb, 1);
    // SA-out: ksplit=4 (xb/qkvb dead -> partials 2,3 alias them)
    gemm(ctxb, wA + 3 * WSZ, nullptr, parts, nullptr, MROWS, DMODEL, DMODEL,
         DMODEL, DMODEL, DMODEL, 0, 4);
    reduce_ln_kernel<<<MROWS, 256, 0, stream>>>(parts, PSTR, 4, sab + 3 * DMODEL, res,
                                                ln_g + (l * 3 + 1) * DMODEL,
                                                ln_b + (l * 3 + 1) * DMODEL, ctxb, nullptr);

    // ======== cross-attention ========  (ctxb = ln2)
    cvt_kernel<<<(int)((WSZ + 255) / 256), 256, 0, stream>>>(caw, wA, (int)WSZ);
    // CA-q stays ksplit=2 (its reduce writes qkvb, which aliases partials 2,3)
    gemm(ctxb, wA, nullptr, parts, nullptr, MROWS, DMODEL, DMODEL,
         DMODEL, DMODEL, DMODEL, 0, 2);
    reduce_cvtq_kernel<<<MROWS, 256, 0, stream>>>(parts, PSTR, 2, cab, qkvb);
    gemm(membb, wA + WSZ, cab + DMODEL, nullptr, qkvb + DMODEL, MROWS,
         2 * DMODEL, DMODEL, DMODEL, DMODEL, 3 * DMODEL, 0, 1);
    attn_kernel<<<dim3(SEQ / QT, BATCH * NHEAD), 256, 0, stream>>>(qkvb, srct, ctxb, 0);
    // CA-out: ksplit=4 (xb/qkvb dead again)
    gemm(ctxb, wA + 3 * WSZ, nullptr, parts, nullptr, MROWS, DMODEL, DMODEL,
         DMODEL, DMODEL, DMODEL, 0, 4);
    reduce_ln_kernel<<<MROWS, 256, 0, stream>>>(parts, PSTR, 4, cab + 3 * DMODEL, res,
                                                ln_g + (l * 3 + 2) * DMODEL,
                                                ln_b + (l * 3 + 2) * DMODEL, ctxb, nullptr);

    // ======== FFN ========  (ctxb = ln3)
    cvt_kernel<<<(int)((DFFN * (long)DMODEL / 4 + 255) / 256), 256, 0, stream>>>(
        ff_w1 + (long)l * DFFN * DMODEL, wF1, (int)(DFFN * (long)DMODEL / 4));
    cvt_kernel<<<(int)((DFFN * (long)DMODEL / 4 + 255) / 256), 256, 0, stream>>>(
        ff_w2 + (long)l * DFFN * DMODEL, wF2, (int)(DFFN * (long)DMODEL / 4));
    gemm(ctxb, wF1, ff_b1 + (long)l * DFFN, nullptr, ffh, MROWS, DFFN,
         DMODEL, DMODEL, DMODEL, DFFN, 1, 1);
    gemm(ffh, wF2, nullptr, parts, nullptr, MROWS, DMODEL, DFFN,
         DFFN, DFFN, DMODEL, 0, 4);
    if (l < NLAYER - 1) {
      reduce_ln_kernel<<<MROWS, 256, 0, stream>>>(parts, PSTR, 4, ff_b2 + (long)l * DMODEL,
                                                  res, ln_g + ((l + 1) * 3) * DMODEL,
                                                  ln_b + ((l + 1) * 3) * DMODEL, ctxb, nullptr);
    } else {
      reduce_ln_kernel<<<MROWS, 256, 0, stream>>>(parts, PSTR, 4, ff_b2 + (long)l * DMODEL,
                                                  res, out_g, out_b, nullptr, out);
    }
  }
}

// Round 10
// 1944.492 us; speedup vs baseline: 1.1357x; 1.0742x over previous
//
#include <hip/hip_runtime.h>
#include <math.h>
#include <stdint.h>

typedef __bf16 bf16_t;
typedef __bf16 bf16x8 __attribute__((ext_vector_type(8)));
typedef __bf16 bf16x4 __attribute__((ext_vector_type(4)));
typedef float f32x4 __attribute__((ext_vector_type(4)));

#define NLAYER 6
#define DMODEL 768
#define NHEAD 12
#define DHEAD 64
#define SEQ 512
#define BATCH 8
#define MROWS 4096 /* BATCH*SEQ */
#define DFFN 3072

// ---------- helpers ----------

__device__ inline void async_load16(const void* g, void* lds) {
  const __attribute__((address_space(1))) void* gp =
      (const __attribute__((address_space(1))) void*)(uintptr_t)g;
  __attribute__((address_space(3))) void* lp =
      (__attribute__((address_space(3))) void*)(uint32_t)(uintptr_t)lds;
  __builtin_amdgcn_global_load_lds(gp, lp, 16, 0, 0);
}

#define VMCNT(n) __builtin_amdgcn_s_waitcnt(0x0F70 | (n))
#define LGKM0 __builtin_amdgcn_s_waitcnt(0xC07F) /* lgkmcnt(0) only */

__device__ inline float wsum(float v) {
#pragma unroll
  for (int o = 32; o > 0; o >>= 1) v += __shfl_xor(v, o, 64);
  return v;
}

__device__ inline float gelu_f(float x) {
  // 0.5x(1+tanh(u)) == x / (1 + exp(-2u)); hardware v_exp_f32 path
  const float u = x + 0.044715f * x * x * x;
  return x / (1.0f + __expf(-1.5957691216057308f * u));
}

struct GP {
  const bf16_t* A;
  const bf16_t* B;
  const float* bias;   // [N] or null (ignored when ksplit>1)
  float* outF;         // f32 out (partial base when ksplit>1)
  bf16_t* outB;        // bf16 out or null
  int M, N, K;
  int lda, ldb, ldc;
  long pstride;  // partial-buffer stride (elements) for ksplit>1
  int act;       // 1 = gelu
  int ksplit;
};

// ---------- 128x128 GEMM (r6 proven config; byte-identical to r9) ----------
__global__ __launch_bounds__(256) void gemm128(GP p) {
  __shared__ __align__(16) char smem[49152];
  bf16_t* As = (bf16_t*)smem;            // [3][128*32]
  bf16_t* Bs = (bf16_t*)(smem + 24576);  // [3][128*32]
  const int tid = threadIdx.x;
  const int wave = tid >> 6, lane = tid & 63;
  const int wr = wave >> 1, wc = wave & 1;
  const int lrow = lane & 15, kq = lane >> 4;
  const int swz = (kq ^ ((lrow >> 1) & 3)) * 8;  // read slot (elements)
  const int sr = tid >> 2;
  const int scs = ((tid & 3) ^ ((tid >> 3) & 3)) << 3;  // inv-swizzled src col
  const int m0 = blockIdx.x * 128;
  const int n0 = blockIdx.y * 128;
  const int zs = (int)blockIdx.z;

  const int kc = p.K / p.ksplit;
  const int kstart = zs * kc;
  const int kend = kstart + kc;

  auto stage = [&](int k0, int buf) {
#pragma unroll
    for (int r = 0; r < 2; ++r)
      async_load16(p.A + (long)(m0 + r * 64 + sr) * p.lda + (k0 + scs),
                   As + buf * 4096 + (r * 64 + wave * 16) * 32);
#pragma unroll
    for (int r = 0; r < 2; ++r)
      async_load16(p.B + (long)(n0 + r * 64 + sr) * p.ldb + (k0 + scs),
                   Bs + buf * 4096 + (r * 64 + wave * 16) * 32);
  };

  f32x4 acc[4][4] = {};
  stage(kstart, 0);
  if (kstart + 32 < kend) stage(kstart + 32, 1);
  int cur = 0, nxt = 1, fut = 2;

  for (int k0 = kstart; k0 < kend; k0 += 32) {
    if (k0 + 64 < kend) {
      stage(k0 + 64, fut);  // fut's last readers finished 2 barriers ago
      VMCNT(8);             // cur's 4 loads (issued 2 iters ago) landed
    } else if (k0 + 32 < kend) {
      VMCNT(4);
    } else {
      VMCNT(0);
    }
    __builtin_amdgcn_s_barrier();

    const int cb = cur * 4096;
    bf16x8 af[4], bfr[4];
#pragma unroll
    for (int i = 0; i < 4; ++i)
      af[i] = *(const bf16x8*)&As[cb + (wr * 64 + i * 16 + lrow) * 32 + swz];
#pragma unroll
    for (int j = 0; j < 4; ++j)
      bfr[j] = *(const bf16x8*)&Bs[cb + (wc * 64 + j * 16 + lrow) * 32 + swz];
#pragma unroll
    for (int i = 0; i < 4; ++i)
#pragma unroll
      for (int j = 0; j < 4; ++j)
        acc[i][j] = __builtin_amdgcn_mfma_f32_16x16x32_bf16(af[i], bfr[j], acc[i][j], 0, 0, 0);

    __builtin_amdgcn_s_barrier();  // all waves done reading cur before reuse
    const int t = cur; cur = nxt; nxt = fut; fut = t;
  }

  // ---- epilogue: LDS-bounce coalesced stores (staging LDS is dead) ----
  const int colbase = n0 + wc * 64;
  const int lc = lrow;  // lane & 15
  float* eb = (float*)(smem + wave * 4608);  // per-wave 4.6KB private

  if (p.ksplit > 1) {
    float* po = p.outF + (long)zs * p.pstride;
#pragma unroll
    for (int i = 0; i < 4; ++i) {
      const int rg0 = m0 + wr * 64 + i * 16;
#pragma unroll
      for (int j = 0; j < 4; ++j)
#pragma unroll
        for (int r = 0; r < 4; ++r)
          eb[(kq * 4 + r) * 68 + j * 16 + lc] = acc[i][j][r];
      LGKM0;
#pragma unroll
      for (int q = 0; q < 4; ++q) {
        const int row = q * 4 + kq;
        const f32x4 v = *(const f32x4*)&eb[row * 68 + lc * 4];
        *(f32x4*)&po[(long)(rg0 + row) * p.ldc + colbase + lc * 4] = v;
      }
      LGKM0;  // reads retired before next i overwrites
    }
  } else {
    float bs[4] = {0.f, 0.f, 0.f, 0.f};
    if (p.bias) {
#pragma unroll
      for (int j = 0; j < 4; ++j) bs[j] = p.bias[colbase + j * 16 + lc];
    }
    bf16_t* bh = (bf16_t*)eb;  // stride 72 (144B = 9x16B, quad-rotating)
    const int l8r = lane >> 3, l8c = lane & 7;
#pragma unroll
    for (int i = 0; i < 4; ++i) {
      const int rg0 = m0 + wr * 64 + i * 16;
#pragma unroll
      for (int j = 0; j < 4; ++j)
#pragma unroll
        for (int r = 0; r < 4; ++r) {
          float y = acc[i][j][r] + bs[j];
          if (p.act) y = gelu_f(y);
          bh[(kq * 4 + r) * 72 + j * 16 + lc] = (bf16_t)y;
        }
      LGKM0;
      if (p.outB) {
#pragma unroll
        for (int q = 0; q < 2; ++q) {
          const int row = q * 8 + l8r;
          const bf16x8 v = *(const bf16x8*)&bh[row * 72 + l8c * 8];
          *(bf16x8*)&p.outB[(long)(rg0 + row) * p.ldc + colbase + l8c * 8] = v;
        }
      }
      LGKM0;
    }
  }
}

// ---------- fused flash attention ----------
#define QT 64
#define KT 128
#define VPAD 136

// NEW (this round): K double-buffer + cross-phase prefetch, the gemm128
// pattern applied to attn. Next tile's K (global_load_lds) and V (reg
// loads) are issued at the TOP of the compute phase; the post-PV barrier's
// implicit vmcnt(0) then waits on loads issued a full phase (~2500cy) ago
// -> per-tile exposed HBM/L2 latency ~0 (was: full latency at the staging
// barrier every tile). LDS 76KB -> still 2 blocks/CU. V-scatter swizzle
// kept from r8/r9 (mapping HW-validated).
__global__ __launch_bounds__(256) void attn_kernel(const bf16_t* __restrict__ qkv,
                                                   const int* __restrict__ toks,
                                                   bf16_t* __restrict__ ctx, int causal) {
  __shared__ __align__(16) bf16_t Qs[QT * 64];
  __shared__ __align__(16) bf16_t Ks[2][KT * 64];
  __shared__ __align__(16) bf16_t Vs[64 * VPAD];
  __shared__ __align__(16) bf16_t Ps[QT * VPAD];
  __shared__ int Ts[SEQ];
  const int tid = threadIdx.x;
  const int wave = tid >> 6, lane = tid & 63;
  const int lm = lane & 15, lq = lane >> 4;
  const int q0 = blockIdx.x * QT;
  const int bh = blockIdx.y;
  const int b = bh / NHEAD, h = bh % NHEAD;
  const long rowbase = (long)b * SEQ;
  const int LD = 3 * DMODEL;
  const bf16_t* Qg = qkv + (rowbase + q0) * LD + h * DHEAD;
  const bf16_t* Kg = qkv + rowbase * LD + DMODEL + h * DHEAD;
  const bf16_t* Vg = qkv + rowbase * LD + 2 * DMODEL + h * DHEAD;

  Ts[tid] = toks[b * SEQ + tid];
  Ts[tid + 256] = toks[b * SEQ + tid + 256];

  auto issueK = [&](int s0, int buf) {
#pragma unroll
    for (int r = 0; r < 4; ++r) {
      const int c = r * 256 + tid;
      const int row = c >> 3, c8 = (c & 7) * 8;
      async_load16(Kg + (long)(s0 + row) * LD + c8, &Ks[buf][c * 8]);
    }
  };
  bf16x8 vv[4];
  auto loadV = [&](int s0) {
#pragma unroll
    for (int r = 0; r < 4; ++r) {
      const int c = r * 256 + tid;
      const int row = c >> 3, c8 = (c & 7) * 8;
      vv[r] = *(const bf16x8*)(Vg + (long)(s0 + row) * LD + c8);
    }
  };
  auto scatterV = [&]() {
#pragma unroll
    for (int r = 0; r < 4; ++r) {
      const int c = r * 256 + tid;
      const int row = c >> 3, c8 = (c & 7) * 8;
      const int sx = c & 7;  // == d>>3 for every d in [c8, c8+8)
#pragma unroll
      for (int j = 0; j < 8; ++j) Vs[(c8 + (j ^ sx)) * VPAD + row] = vv[r][j];
    }
  };

#pragma unroll
  for (int r = 0; r < 2; ++r) {
    const int c = r * 256 + tid;
    const int row = c >> 3, c8 = (c & 7) * 8;
    async_load16(Qg + (long)row * LD + c8, &Qs[c * 8]);
  }
  issueK(0, 0);
  loadV(0);
  __syncthreads();  // Q + K0 landed; Ts visible (vv waited at first use)

  bf16x8 aQ0 = *(const bf16x8*)&Qs[(wave * 16 + lm) * 64 + lq * 8];
  bf16x8 aQ1 = *(const bf16x8*)&Qs[(wave * 16 + lm) * 64 + 32 + lq * 8];

  scatterV();
  __syncthreads();  // Vs(tile 0) visible

  float m_i[4], l_i[4];
  f32x4 O[4] = {};
#pragma unroll
  for (int r = 0; r < 4; ++r) { m_i[r] = -3.0e38f; l_i[r] = 0.0f; }

  const int s_end = causal ? (q0 + QT) : SEQ;
  int cur = 0;
  for (int s0 = 0; s0 < s_end; s0 += KT) {
    const bool hn = (s0 + KT) < s_end;
    if (hn) {
      issueK(s0 + KT, cur ^ 1);  // lands by the post-PV barrier
      loadV(s0 + KT);            // reg loads, consumed after that barrier
    }

    f32x4 sv[8];
#pragma unroll
    for (int jt = 0; jt < 8; ++jt) {
      const bf16x8 b0 = *(const bf16x8*)&Ks[cur][(jt * 16 + lm) * 64 + lq * 8];
      const bf16x8 b1 = *(const bf16x8*)&Ks[cur][(jt * 16 + lm) * 64 + 32 + lq * 8];
      f32x4 a = {};
      a = __builtin_amdgcn_mfma_f32_16x16x32_bf16(aQ0, b0, a, 0, 0, 0);
      a = __builtin_amdgcn_mfma_f32_16x16x32_bf16(aQ1, b1, a, 0, 0, 0);
      sv[jt] = a;
    }

#pragma unroll
    for (int r = 0; r < 4; ++r) {
      const int qa = q0 + wave * 16 + lq * 4 + r;
      float sr[8];
      float mx = -3.0e38f;
#pragma unroll
      for (int jt = 0; jt < 8; ++jt) {
        const int k = s0 + jt * 16 + lm;
        const float x = sv[jt][r] * 0.125f;
        const bool msk = (Ts[k] == 0) || (causal && (k > qa));
        sr[jt] = msk ? -1.0e18f : x;
        mx = fmaxf(mx, sr[jt]);
      }
#pragma unroll
      for (int o = 1; o < 16; o <<= 1) mx = fmaxf(mx, __shfl_xor(mx, o, 64));
      const float mn = fmaxf(m_i[r], mx);
      const float alpha = __expf(m_i[r] - mn);
      float sum = 0.0f;
#pragma unroll
      for (int jt = 0; jt < 8; ++jt) {
        const float pv = __expf(sr[jt] - mn);
        sr[jt] = pv;
        sum += pv;
      }
#pragma unroll
      for (int o = 1; o < 16; o <<= 1) sum += __shfl_xor(sum, o, 64);
      l_i[r] = l_i[r] * alpha + sum;
      m_i[r] = mn;
#pragma unroll
      for (int jn = 0; jn < 4; ++jn) O[jn][r] *= alpha;
#pragma unroll
      for (int jt = 0; jt < 8; ++jt)
        Ps[(wave * 16 + lq * 4 + r) * VPAD + jt * 16 + lm] = (bf16_t)sr[jt];
    }

#pragma unroll
    for (int kt = 0; kt < 4; ++kt) {
      const bf16x8 aP = *(const bf16x8*)&Ps[(wave * 16 + lm) * VPAD + kt * 32 + lq * 8];
#pragma unroll
      for (int jn = 0; jn < 4; ++jn) {
        const int Dn = jn * 16 + lm;
        const bf16x8 bV =
            *(const bf16x8*)&Vs[(Dn ^ ((Dn >> 3) & 7)) * VPAD + kt * 32 + lq * 8];
        O[jn] = __builtin_amdgcn_mfma_f32_16x16x32_bf16(aP, bV, O[jn], 0, 0, 0);
      }
    }

    __syncthreads();  // all waves done with Vs/Ks[cur]; prefetches landed
    if (hn) scatterV();
    __syncthreads();  // next Vs visible
    cur ^= 1;
  }

#pragma unroll
  for (int r = 0; r < 4; ++r) {
    const int q = q0 + wave * 16 + lq * 4 + r;
    const float inv = 1.0f / l_i[r];
#pragma unroll
    for (int jn = 0; jn < 4; ++jn) {
      const int d = jn * 16 + lm;
      ctx[(rowbase + q) * DMODEL + h * DHEAD + d] = (bf16_t)(O[jn][r] * inv);
    }
  }
}

// ---------- LayerNorm (row = 768) ----------
__global__ __launch_bounds__(256) void ln_kernel(const float* __restrict__ X,
                                                 const float* __restrict__ g,
                                                 const float* __restrict__ b,
                                                 bf16_t* __restrict__ outB,
                                                 float* __restrict__ outF) {
  const int row = blockIdx.x, tid = threadIdx.x;
  const float* xr = X + (long)row * DMODEL;
  const float v0 = xr[tid], v1 = xr[tid + 256], v2 = xr[tid + 512];
  __shared__ float r1[4], r2[4];
  const int wv = tid >> 6, ln = tid & 63;
  float s = wsum(v0 + v1 + v2);
  if (ln == 0) r1[wv] = s;
  __syncthreads();
  const float mean = (r1[0] + r1[1] + r1[2] + r1[3]) * (1.0f / DMODEL);
  const float d0 = v0 - mean, d1 = v1 - mean, d2 = v2 - mean;
  float q = wsum(d0 * d0 + d1 * d1 + d2 * d2);
  if (ln == 0) r2[wv] = q;
  __syncthreads();
  const float var = (r2[0] + r2[1] + r2[2] + r2[3]) * (1.0f / DMODEL);
  const float rs = rsqrtf(var + 1e-6f);
  const float y0 = d0 * rs * g[tid] + b[tid];
  const float y1 = d1 * rs * g[tid + 256] + b[tid + 256];
  const float y2 = d2 * rs * g[tid + 512] + b[tid + 512];
  const long base = (long)row * DMODEL;
  if (outB) {
    outB[base + tid] = (bf16_t)y0;
    outB[base + tid + 256] = (bf16_t)y1;
    outB[base + tid + 512] = (bf16_t)y2;
  }
  if (outF) {
    outF[base + tid] = y0;
    outF[base + tid + 256] = y1;
    outF[base + tid + 512] = y2;
  }
}

// ---------- reduce split-K partials + bias + residual, then LayerNorm ----------
__global__ __launch_bounds__(256) void reduce_ln_kernel(
    const float* __restrict__ parts, long pstr, int np,
    const float* __restrict__ bias, float* __restrict__ res,
    const float* __restrict__ g, const float* __restrict__ b,
    bf16_t* __restrict__ outB, float* __restrict__ outF) {
  const int row = blockIdx.x, tid = threadIdx.x;
  const long base = (long)row * DMODEL;
  float v0, v1, v2;
  {
    float t0 = res[base + tid] + bias[tid];
    float t1 = res[base + tid + 256] + bias[tid + 256];
    float t2 = res[base + tid + 512] + bias[tid + 512];
    for (int p = 0; p < np; ++p) {
      const float* pp = parts + p * pstr + base;
      t0 += pp[tid];
      t1 += pp[tid + 256];
      t2 += pp[tid + 512];
    }
    v0 = t0; v1 = t1; v2 = t2;
    res[base + tid] = t0;
    res[base + tid + 256] = t1;
    res[base + tid + 512] = t2;
  }
  __shared__ float r1[4], r2[4];
  const int wv = tid >> 6, ln = tid & 63;
  float s = wsum(v0 + v1 + v2);
  if (ln == 0) r1[wv] = s;
  __syncthreads();
  const float mean = (r1[0] + r1[1] + r1[2] + r1[3]) * (1.0f / DMODEL);
  const float d0 = v0 - mean, d1 = v1 - mean, d2 = v2 - mean;
  float q = wsum(d0 * d0 + d1 * d1 + d2 * d2);
  if (ln == 0) r2[wv] = q;
  __syncthreads();
  const float var = (r2[0] + r2[1] + r2[2] + r2[3]) * (1.0f / DMODEL);
  const float rs = rsqrtf(var + 1e-6f);
  const float y0 = d0 * rs * g[tid] + b[tid];
  const float y1 = d1 * rs * g[tid + 256] + b[tid + 256];
  const float y2 = d2 * rs * g[tid + 512] + b[tid + 512];
  if (outB) {
    outB[base + tid] = (bf16_t)y0;
    outB[base + tid + 256] = (bf16_t)y1;
    outB[base + tid + 512] = (bf16_t)y2;
  }
  if (outF) {
    outF[base + tid] = y0;
    outF[base + tid + 256] = y1;
    outF[base + tid + 512] = y2;
  }
}

// ---------- reduce split-K partials + bias -> strided bf16 (CA-q into qkv) ----------
__global__ __launch_bounds__(256) void reduce_cvtq_kernel(
    const float* __restrict__ parts, long pstr, int np,
    const float* __restrict__ bias, bf16_t* __restrict__ o) {
  const int row = blockIdx.x, tid = threadIdx.x;
  const long base = (long)row * DMODEL;
  const long ob = (long)row * 3 * DMODEL;
#pragma unroll
  for (int c = 0; c < 3; ++c) {
    const int col = tid + c * 256;
    float t = bias[col];
    for (int p = 0; p < np; ++p) t += parts[p * pstr + base + col];
    o[ob + col] = (bf16_t)t;
  }
}

// ---------- embedding * sqrt(D) + sinusoidal PE ----------
__global__ __launch_bounds__(256) void emb_kernel(const int* __restrict__ tgt,
                                                  const float* __restrict__ tab,
                                                  float* __restrict__ res) {
  const int row = blockIdx.x;
  const int t = row & (SEQ - 1);
  const long tok = tgt[row];
  const float* er = tab + tok * DMODEL;
  float* orow = res + (long)row * DMODEL;
  const float c1 = -9.210340371976184f / 768.0f;
  for (int c = threadIdx.x; c < DMODEL; c += 256) {
    const float e = er[c] * 27.712812921102035f;
    const float div = expf((float)(c & ~1) * c1);
    const float ang = (float)t * div;
    const float pe = (c & 1) ? cosf(ang) : sinf(ang);
    orow[c] = e + pe;
  }
}

// ---------- f32 -> bf16 convert (n4 = n/4) ----------
__global__ __launch_bounds__(256) void cvt_kernel(const float* __restrict__ in,
                                                  bf16_t* __restrict__ o, int n4) {
  const int i = blockIdx.x * 256 + threadIdx.x;
  if (i < n4) {
    const float4 v = ((const float4*)in)[i];
    bf16x4 r = {(bf16_t)v.x, (bf16_t)v.y, (bf16_t)v.z, (bf16_t)v.w};
    ((bf16x4*)o)[i] = r;
  }
}

// ---------- fused dual f32 -> bf16 convert (contiguous dest o, o+4*n4each) ----------
__global__ __launch_bounds__(256) void cvt2_kernel(const float* __restrict__ in1,
                                                   const float* __restrict__ in2,
                                                   bf16_t* __restrict__ o, int n4each) {
  const int i = blockIdx.x * 256 + threadIdx.x;
  const float* in = (i < n4each) ? in1 + (long)i * 4 : in2 + (long)(i - n4each) * 4;
  if (i < 2 * n4each) {
    const float4 v = *(const float4*)in;
    bf16x4 r = {(bf16_t)v.x, (bf16_t)v.y, (bf16_t)v.z, (bf16_t)v.w};
    ((bf16x4*)o)[i] = r;
  }
}

// ---------- host ----------
extern "C" void kernel_launch(void* const* d_in, const int* in_sizes, int n_in,
                              void* d_out, int out_size, void* d_ws, size_t ws_size,
                              hipStream_t stream) {
  (void)in_sizes; (void)n_in; (void)out_size; (void)ws_size;
  const int* tgt = (const int*)d_in[0];
  const int* srct = (const int*)d_in[1];
  const float* memb = (const float*)d_in[2];
  const float* embt = (const float*)d_in[3];
  const float* sa_w = (const float*)d_in[4];
  const float* sa_b = (const float*)d_in[5];
  const float* ca_w = (const float*)d_in[6];
  const float* ca_b = (const float*)d_in[7];
  const float* ln_g = (const float*)d_in[8];
  const float* ln_b = (const float*)d_in[9];
  const float* ff_w1 = (const float*)d_in[10];
  const float* ff_b1 = (const float*)d_in[11];
  const float* ff_w2 = (const float*)d_in[12];
  const float* ff_b2 = (const float*)d_in[13];
  const float* out_g = (const float*)d_in[14];
  const float* out_b = (const float*)d_in[15];
  float* out = (float*)d_out;

  char* wsb = (char*)d_ws;
  size_t off = 0;
  auto alloc = [&](size_t bytes) -> void* {
    void* pp = wsb + off;
    off = (off + bytes + 255) & ~(size_t)255;
    return pp;
  };
  // Allocation ORDER/SIZES load-bearing: ksplit=4 partials span
  // parts(2*PSTR) + xb + qkvb exactly (xb+qkvb are DEAD at every ksplit=4
  // GEMM: all LN outputs live in ctxb, never xb). wF1 immediately precedes
  // wF2 (size multiple of 256) -> cvt2_kernel writes both contiguously.
  float* res = (float*)alloc((size_t)MROWS * DMODEL * 4);
  float* parts = (float*)alloc((size_t)2 * MROWS * DMODEL * 4);  // partials 0..1
  bf16_t* xb = (bf16_t*)alloc((size_t)MROWS * DMODEL * 2);       // partial 2 space
  bf16_t* qkvb = (bf16_t*)alloc((size_t)MROWS * 3 * DMODEL * 2); // partial 2/3 space
  bf16_t* ctxb = (bf16_t*)alloc((size_t)MROWS * DMODEL * 2);
  bf16_t* membb = (bf16_t*)alloc((size_t)MROWS * DMODEL * 2);
  bf16_t* ffh = (bf16_t*)alloc((size_t)MROWS * DFFN * 2);
  bf16_t* wA = (bf16_t*)alloc((size_t)4 * DMODEL * DMODEL * 2);
  bf16_t* wF1 = (bf16_t*)alloc((size_t)DFFN * DMODEL * 2);
  bf16_t* wF2 = (bf16_t*)alloc((size_t)DFFN * DMODEL * 2);
  (void)xb;
  (void)wF2;  // == wF1 + DFFN*DMODEL (alloc rounding exact)

  const long PSTR = (long)MROWS * DMODEL;

  auto gemm = [&](const bf16_t* A, const bf16_t* Bm, const float* bias,
                  float* oF, bf16_t* oB, int M, int N, int K,
                  int lda, int ldb, int ldc, int act, int ksplit) {
    GP p{A, Bm, bias, oF, oB, M, N, K, lda, ldb, ldc, PSTR, act, ksplit};
    dim3 g((unsigned)(M / 128), (unsigned)(N / 128), (unsigned)ksplit);
    gemm128<<<g, 256, 0, stream>>>(p);
  };

  const long WSZ = (long)DMODEL * DMODEL;
  const int FN4 = (int)(DFFN * (long)DMODEL / 4);

  emb_kernel<<<MROWS, 256, 0, stream>>>(tgt, embt, res);
  cvt_kernel<<<(MROWS * DMODEL / 4 + 255) / 256, 256, 0, stream>>>(memb, membb,
                                                                   MROWS * DMODEL / 4);
  ln_kernel<<<MROWS, 256, 0, stream>>>(res, ln_g, ln_b, ctxb, nullptr);

  for (int l = 0; l < NLAYER; ++l) {
    const float* saw = sa_w + (long)l * 4 * WSZ;
    const float* sab = sa_b + (long)l * 4 * DMODEL;
    const float* caw = ca_w + (long)l * 4 * WSZ;
    const float* cab = ca_b + (long)l * 4 * DMODEL;

    // ======== self-attention ========   (ctxb = ln1)
    cvt_kernel<<<(int)((WSZ + 255) / 256), 256, 0, stream>>>(saw, wA, (int)WSZ);
    gemm(ctxb, wA, sab, nullptr, qkvb, MROWS, 3 * DMODEL, DMODEL,
         DMODEL, DMODEL, 3 * DMODEL, 0, 1);
    attn_kernel<<<dim3(SEQ / QT, BATCH * NHEAD), 256, 0, stream>>>(qkvb, tgt, ctxb, 1);
    // SA-out: ksplit=4 (xb/qkvb dead -> partials 2,3 alias them)
    gemm(ctxb, wA + 3 * WSZ, nullptr, parts, nullptr, MROWS, DMODEL, DMODEL,
         DMODEL, DMODEL, DMODEL, 0, 4);
    reduce_ln_kernel<<<MROWS, 256, 0, stream>>>(parts, PSTR, 4, sab + 3 * DMODEL, res,
                                                ln_g + (l * 3 + 1) * DMODEL,
                                                ln_b + (l * 3 + 1) * DMODEL, ctxb, nullptr);

    // ======== cross-attention ========  (ctxb = ln2)
    cvt_kernel<<<(int)((WSZ + 255) / 256), 256, 0, stream>>>(caw, wA, (int)WSZ);
    // CA-q stays ksplit=2 (its reduce writes qkvb, which aliases partials 2,3)
    gemm(ctxb, wA, nullptr, parts, nullptr, MROWS, DMODEL, DMODEL,
         DMODEL, DMODEL, DMODEL, 0, 2);
    reduce_cvtq_kernel<<<MROWS, 256, 0, stream>>>(parts, PSTR, 2, cab, qkvb);
    gemm(membb, wA + WSZ, cab + DMODEL, nullptr, qkvb + DMODEL, MROWS,
         2 * DMODEL, DMODEL, DMODEL, DMODEL, 3 * DMODEL, 0, 1);
    attn_kernel<<<dim3(SEQ / QT, BATCH * NHEAD), 256, 0, stream>>>(qkvb, srct, ctxb, 0);
    // CA-out: ksplit=4 (xb/qkvb dead again)
    gemm(ctxb, wA + 3 * WSZ, nullptr, parts, nullptr, MROWS, DMODEL, DMODEL,
         DMODEL, DMODEL, DMODEL, 0, 4);
    reduce_ln_kernel<<<MROWS, 256, 0, stream>>>(parts, PSTR, 4, cab + 3 * DMODEL, res,
                                                ln_g + (l * 3 + 2) * DMODEL,
                                                ln_b + (l * 3 + 2) * DMODEL, ctxb, nullptr);

    // ======== FFN ========  (ctxb = ln3)
    cvt2_kernel<<<(int)((2 * FN4 + 255) / 256), 256, 0, stream>>>(
        ff_w1 + (long)l * DFFN * DMODEL, ff_w2 + (long)l * DFFN * DMODEL, wF1, FN4);
    gemm(ctxb, wF1, ff_b1 + (long)l * DFFN, nullptr, ffh, MROWS, DFFN,
         DMODEL, DMODEL, DMODEL, DFFN, 1, 1);
    gemm(ffh, wF1 + (long)DFFN * DMODEL, nullptr, parts, nullptr, MROWS, DMODEL, DFFN,
         DFFN, DFFN, DMODEL, 0, 4);
    if (l < NLAYER - 1) {
      reduce_ln_kernel<<<MROWS, 256, 0, stream>>>(parts, PSTR, 4, ff_b2 + (long)l * DMODEL,
                                                  res, ln_g + ((l + 1) * 3) * DMODEL,
                                                  ln_b + ((l + 1) * 3) * DMODEL, ctxb, nullptr);
    } else {
      reduce_ln_kernel<<<MROWS, 256, 0, stream>>>(parts, PSTR, 4, ff_b2 + (long)l * DMODEL,
                                                  res, out_g, out_b, nullptr, out);
    }
  }
}